// Round 4
// baseline (3951.151 us; speedup 1.0000x reference)
//
#include <hip/hip_runtime.h>
#include <stdint.h>

#define C_SIG 1.702f
#define MM 32
#define TT 16
#define SS 8
#define NSAMP 64

// JAX threefry-2x32, 20 rounds.
__device__ __forceinline__ void tf2x32(uint32_t k0, uint32_t k1,
                                       uint32_t x0, uint32_t x1,
                                       uint32_t& o0, uint32_t& o1) {
  const uint32_t k2 = k0 ^ k1 ^ 0x1BD11BDAu;
  x0 += k0; x1 += k1;
#define TFR(r) { x0 += x1; x1 = (x1 << (r)) | (x1 >> (32 - (r))); x1 ^= x0; }
  TFR(13) TFR(15) TFR(26) TFR(6)
  x0 += k1; x1 += k2 + 1u;
  TFR(17) TFR(29) TFR(16) TFR(24)
  x0 += k2; x1 += k0 + 2u;
  TFR(13) TFR(15) TFR(26) TFR(6)
  x0 += k0; x1 += k1 + 3u;
  TFR(17) TFR(29) TFR(16) TFR(24)
  x0 += k1; x1 += k2 + 4u;
  TFR(13) TFR(15) TFR(26) TFR(6)
  x0 += k2; x1 += k0 + 5u;
#undef TFR
  o0 = x0; o1 = x1;
}

// JAX gumbel from 32 random bits (partitionable: b = out0^out1):
// u = max(tiny, bitcast((b>>9)|1.0f)-1), g = -log(-log(u))
__device__ __forceinline__ float gumbel_bits(uint32_t b) {
  float f = __uint_as_float((b >> 9) | 0x3F800000u) - 1.0f;
  float u = fmaxf(f, 1.17549435e-38f);
  return -logf(-logf(u));
}

// jax.nn.log_sigmoid(x) = min(x,0) - log1p(exp(-|x|))
__device__ __forceinline__ float lsig(float x) {
  return fminf(x, 0.0f) - log1pf(expf(-fabsf(x)));
}

__global__ __launch_bounds__(512) void mfs_net_kernel(
    const float* __restrict__ log_qi,
    const float* __restrict__ G,
    const float* __restrict__ rho,
    const float* __restrict__ syms_in,
    float* __restrict__ out, int N)
{
  __shared__ float sG[MM][TT];        // sqrt_2rho * G  (2 KB)
  __shared__ float lq[TT][SS];        // running logits (0.5 KB)
  __shared__ float ssym[TT][NSAMP];   // sampled symbols (4 KB)
  __shared__ float base_s[MM][NSAMP]; // per-m partial dot (8 KB)
  __shared__ float ex_s[SS];
  __shared__ float syms[SS];

  const int n   = blockIdx.x;
  const int tid = threadIdx.x;

  const float srho = rho[n];
  // MM*TT == 512 == blockDim.x: one sG element per thread
  ((float*)sG)[tid] = srho * G[(size_t)n * (MM * TT) + tid];
  if (tid < TT * SS) ((float*)lq)[tid] = log_qi[(size_t)n * (TT * SS) + tid];
  if (tid < SS) syms[tid] = syms_in[tid];
  __syncthreads();

  #pragma clang loop unroll(disable)
  for (int xi = 0; xi < TT; ++xi) {
    // step key = fold_in(key(42), xi) = threefry((0,42),(0,xi))
    uint32_t kk0, kk1;
    tf2x32(0u, 42u, 0u, (uint32_t)xi, kk0, kk1);

    // ---- Phase A: categorical sampling, partitionable threefry.
    // Element (ns,n,t,s) uses counter x=(0, flat), bits = o0^o1,
    // flat = ((ns*N+n)*16+t)*8+s. 1024 (t,ns) units, 2 per thread.
    #pragma clang loop unroll(disable)
    for (int rep = 0; rep < 2; ++rep) {
      const int u  = tid + rep * 512;
      const int t  = u >> 6;    // 0..15
      const int ns = u & 63;    // 0..63
      if (t != xi) {            // row xi's samples are never used
        const uint32_t f0 =
            (((uint32_t)ns * (uint32_t)N + (uint32_t)n) * 16u + (uint32_t)t) * 8u;
        float bv = -3.402823466e38f;
        int bi = 0;
        #pragma clang loop unroll(disable)
        for (int s = 0; s < SS; ++s) {
          uint32_t o0, o1;
          tf2x32(kk0, kk1, 0u, f0 + (uint32_t)s, o0, o1);
          const float v = gumbel_bits(o0 ^ o1) + lq[t][s];
          if (v > bv) { bv = v; bi = s; }
        }
        ssym[t][ns] = syms[bi];
      }
    }
    __syncthreads();

    // ---- Phase B: base[m][ns] = sum_{t != xi} sG[m][t] * ssym[t][ns]
    {
      const int ns = tid & 63;
      const int mg = tid >> 6;  // 0..7 -> m = mg*4+j
      float a0 = 0.f, a1 = 0.f, a2 = 0.f, a3 = 0.f;
      #pragma unroll
      for (int t = 0; t < TT; ++t) {
        if (t == xi) continue;
        const float sv = ssym[t][ns];
        a0 += sG[mg * 4 + 0][t] * sv;
        a1 += sG[mg * 4 + 1][t] * sv;
        a2 += sG[mg * 4 + 2][t] * sv;
        a3 += sG[mg * 4 + 3][t] * sv;
      }
      base_s[mg * 4 + 0][ns] = a0;
      base_s[mg * 4 + 1][ns] = a1;
      base_s[mg * 4 + 2][ns] = a2;
      base_s[mg * 4 + 3][ns] = a3;
    }
    __syncthreads();

    // ---- Phase C: lp[ns][s] = sum_m lsig(C*(base + sG[m][xi]*sym[s])); mean over ns
    {
      const int ns = tid & 63;  // = lane within wave
      const int s  = tid >> 6;  // wave id = constellation point
      const float sym = syms[s];
      float lp = 0.f;
      #pragma unroll
      for (int m = 0; m < MM; ++m) {
        const float term = base_s[m][ns] + sG[m][xi] * sym;
        lp += lsig(C_SIG * term);
      }
      #pragma unroll
      for (int off = 32; off > 0; off >>= 1) lp += __shfl_xor(lp, off, 64);
      if (ns == 0) ex_s[s] = lp * (1.0f / 64.0f);
    }
    __syncthreads();

    // ---- Phase D: write row xi, subtract per-row max (all rows)
    if (tid < TT * SS) {
      const int t = tid >> 3, s = tid & 7;
      float v = (t == xi) ? ex_s[s] : lq[t][s];
      float mx = v;
      #pragma unroll
      for (int off = 1; off < 8; off <<= 1) mx = fmaxf(mx, __shfl_xor(mx, off, 64));
      lq[t][s] = v - mx;
    }
    __syncthreads();
  }

  if (tid < TT * SS) out[(size_t)n * (TT * SS) + tid] = ((float*)lq)[tid];
}

extern "C" void kernel_launch(void* const* d_in, const int* in_sizes, int n_in,
                              void* d_out, int out_size, void* d_ws, size_t ws_size,
                              hipStream_t stream) {
  const float* log_qi = (const float*)d_in[0];
  const float* G      = (const float*)d_in[1];
  const float* rho    = (const float*)d_in[2];
  const float* syms   = (const float*)d_in[3];
  float* out          = (float*)d_out;
  const int N = in_sizes[2];  // 4096
  mfs_net_kernel<<<N, 512, 0, stream>>>(log_qi, G, rho, syms, out, N);
}

// Round 5
// 1272.033 us; speedup vs baseline: 3.1062x; 3.1062x over previous
//
#include <hip/hip_runtime.h>
#include <stdint.h>

#define C_SIG 1.702f
#define MM 32
#define TT 16
#define SS 8
#define LOG2E 1.44269504088896f
#define LN2 0.693147180559945f

// JAX threefry-2x32, 20 rounds. Rotates compile to v_alignbit_b32.
__device__ __forceinline__ void tf2x32(uint32_t k0, uint32_t k1,
                                       uint32_t x0, uint32_t x1,
                                       uint32_t& o0, uint32_t& o1) {
  const uint32_t k2 = k0 ^ k1 ^ 0x1BD11BDAu;
  x0 += k0; x1 += k1;
#define TFR(r) { x0 += x1; x1 = (x1 << (r)) | (x1 >> (32 - (r))); x1 ^= x0; }
  TFR(13) TFR(15) TFR(26) TFR(6)
  x0 += k1; x1 += k2 + 1u;
  TFR(17) TFR(29) TFR(16) TFR(24)
  x0 += k2; x1 += k0 + 2u;
  TFR(13) TFR(15) TFR(26) TFR(6)
  x0 += k0; x1 += k1 + 3u;
  TFR(17) TFR(29) TFR(16) TFR(24)
  x0 += k1; x1 += k2 + 4u;
  TFR(13) TFR(15) TFR(26) TFR(6)
  x0 += k2; x1 += k0 + 5u;
#undef TFR
  o0 = x0; o1 = x1;
}

// fast log_sigmoid: min(x,0) - ln2*log2(1 + exp2(-|x|*log2e))
__device__ __forceinline__ float lsig_fast(float x) {
  const float e = __builtin_amdgcn_exp2f(-LOG2E * fabsf(x));
  const float l = __builtin_amdgcn_logf(1.0f + e);  // log2(1+e)
  return fminf(x, 0.0f) - LN2 * l;
}

__global__ __launch_bounds__(512) void mfs_net_kernel(
    const float* __restrict__ log_qi,
    const float* __restrict__ G,
    const float* __restrict__ rho,
    const float* __restrict__ syms_in,
    float* __restrict__ out, int N)
{
  __shared__ float sG[MM][TT];        // C_SIG * sqrt_2rho * G  (2 KB)
  __shared__ float lq[TT][SS];        // running logits (0.5 KB)
  __shared__ float ssym[TT][64];      // sampled symbols (4 KB)
  __shared__ float base_s[MM][64];    // per-m partial dot (8 KB)
  __shared__ float ex_s[SS];
  __shared__ float syms[SS];

  const int n   = blockIdx.x;
  const int tid = threadIdx.x;

  const float srho = rho[n];
  // MM*TT == 512 == blockDim.x: one sG element per thread. C_SIG folded in.
  ((float*)sG)[tid] = C_SIG * srho * G[(size_t)n * (MM * TT) + tid];
  if (tid < TT * SS) ((float*)lq)[tid] = log_qi[(size_t)n * (TT * SS) + tid];
  if (tid < SS) syms[tid] = syms_in[tid];
  __syncthreads();

  #pragma clang loop unroll(disable)
  for (int xi = 0; xi < TT; ++xi) {
    // step key = fold_in(key(42), xi) = threefry((0,42),(0,xi))
    uint32_t kk0, kk1;
    tf2x32(0u, 42u, 0u, (uint32_t)xi, kk0, kk1);

    // ---- Phase A: categorical sampling (partitionable threefry).
    // Element (ns,n,t,s): counter (0, flat), bits = o0^o1,
    // flat = ((ns*N+n)*16+t)*8+s.
    // argmax_s(gumbel_s + l_s) == argmin_s exp(-l_s) * (-log2(u_s))
    // (monotone transform; positive scale ln2 dropped; row max-normalized so
    //  exp(-l) in [1, inf), inf == "never selected" ~ exact).
    #pragma clang loop unroll(disable)
    for (int rep = 0; rep < 2; ++rep) {
      const int u_idx = tid + rep * 512;
      const int t  = u_idx >> 6;    // 0..15 (wave-uniform)
      const int ns = u_idx & 63;    // 0..63
      if (t != xi) {                // row xi's samples are never used
        const uint32_t f0 =
            (((uint32_t)ns * (uint32_t)N + (uint32_t)n) * 16u + (uint32_t)t) * 8u;
        float bv = 3.402823466e38f;
        int bi = 0;
        #pragma unroll
        for (int s = 0; s < SS; ++s) {
          uint32_t o0, o1;
          tf2x32(kk0, kk1, 0u, f0 + (uint32_t)s, o0, o1);
          const uint32_t b = o0 ^ o1;
          const float f = __uint_as_float((b >> 9) | 0x3F800000u) - 1.0f;
          const float uu = fmaxf(f, 1.17549435e-38f);
          const float nl = -__builtin_amdgcn_logf(uu);               // -log2(u) > 0
          const float w  = __builtin_amdgcn_exp2f(-LOG2E * lq[t][s]); // exp(-l)
          const float v  = w * nl;
          if (v < bv) { bv = v; bi = s; }
        }
        ssym[t][ns] = syms[bi];
      }
    }
    __syncthreads();

    // ---- Phase B: base[m][ns] = sum_{t != xi} sG[m][t] * ssym[t][ns]
    {
      const int ns = tid & 63;
      const int mg = tid >> 6;  // 0..7 -> m = mg*4+j
      float a0 = 0.f, a1 = 0.f, a2 = 0.f, a3 = 0.f;
      #pragma unroll
      for (int t = 0; t < TT; ++t) {
        if (t == xi) continue;
        const float sv = ssym[t][ns];
        a0 += sG[mg * 4 + 0][t] * sv;
        a1 += sG[mg * 4 + 1][t] * sv;
        a2 += sG[mg * 4 + 2][t] * sv;
        a3 += sG[mg * 4 + 3][t] * sv;
      }
      base_s[mg * 4 + 0][ns] = a0;
      base_s[mg * 4 + 1][ns] = a1;
      base_s[mg * 4 + 2][ns] = a2;
      base_s[mg * 4 + 3][ns] = a3;
    }
    __syncthreads();

    // ---- Phase C: lp[ns][s] = sum_m lsig(base + sG[m][xi]*sym[s]); mean over ns
    {
      const int ns = tid & 63;  // = lane within wave
      const int s  = tid >> 6;  // wave id = constellation point
      const float sym = syms[s];
      float lp = 0.f;
      #pragma unroll
      for (int m = 0; m < MM; ++m) {
        lp += lsig_fast(base_s[m][ns] + sG[m][xi] * sym);
      }
      #pragma unroll
      for (int off = 32; off > 0; off >>= 1) lp += __shfl_xor(lp, off, 64);
      if (ns == 0) ex_s[s] = lp * (1.0f / 64.0f);
    }
    __syncthreads();

    // ---- Phase D: write row xi, subtract per-row max (all rows)
    if (tid < TT * SS) {
      const int t = tid >> 3, s = tid & 7;
      float v = (t == xi) ? ex_s[s] : lq[t][s];
      float mx = v;
      #pragma unroll
      for (int off = 1; off < 8; off <<= 1) mx = fmaxf(mx, __shfl_xor(mx, off, 64));
      lq[t][s] = v - mx;
    }
    __syncthreads();
  }

  if (tid < TT * SS) out[(size_t)n * (TT * SS) + tid] = ((float*)lq)[tid];
}

extern "C" void kernel_launch(void* const* d_in, const int* in_sizes, int n_in,
                              void* d_out, int out_size, void* d_ws, size_t ws_size,
                              hipStream_t stream) {
  const float* log_qi = (const float*)d_in[0];
  const float* G      = (const float*)d_in[1];
  const float* rho    = (const float*)d_in[2];
  const float* syms   = (const float*)d_in[3];
  float* out          = (float*)d_out;
  const int N = in_sizes[2];  // 4096
  mfs_net_kernel<<<N, 512, 0, stream>>>(log_qi, G, rho, syms, out, N);
}